// Round 7
// baseline (393.948 us; speedup 1.0000x reference)
//
#include <hip/hip_runtime.h>
#include <hip/hip_bf16.h>
#include <math.h>

#define BATCH   2
#define N_NODES 10000
#define E_EDGES 160000
#define BN      (BATCH * N_NODES)       // 20000
#define BE      (BATCH * E_EDGES)       // 320000
#define ND      128
#define ED      64
#define HID     256
#define K1      320   // 2*ND + ED
#define K2      256
#define K1U     384   // ND + HID
#define NOUT    128
#define TMN     32    // node/pgemm rows per block (20000 = 625*32, exact)
#define TME     64    // edge-kernel rows per block
#define LDH     264   // H stride (bf16), 256+8

typedef __attribute__((ext_vector_type(8))) short bf16x8;
typedef __attribute__((ext_vector_type(4))) float f32x4;

// ---------- static device buffers ----------
__device__ unsigned short g_Pb[(size_t)BN * 512];       // bf16: [n][0:256)=src-part, [256:512)=dst-part
__device__ unsigned short g_nodef_bf[(size_t)BN * ND];  // bf16 node features
__device__ unsigned short g_w1c[HID * K1U];             // node L1 weights n-major bf16:
                                                        //   cols [0,128)  = W1u[0:128]^T
                                                        //   cols [128,384)= (W2m @ W1u[128:384])^T
__device__ unsigned short g_w2ut[K2 * NOUT];            // node L2 weights, n-major bf16
__device__ float          g_bc[HID];                    // b2m @ W1u[128:384]
__device__ int            g_hist[BN];                   // per-dst edge counts

// fast tanh-gelu: tanh(u) = 1 - 2/(exp(2u)+1); both tails saturate correctly.
__device__ __forceinline__ float gelu_tanh(float x) {
    float u = 0.7978845608028654f * (x + 0.044715f * x * x * x);
    float e = __expf(2.0f * u);
    float t = 1.0f - 2.0f * __builtin_amdgcn_rcpf(e + 1.0f);
    return 0.5f * x * (1.0f + t);
}

__device__ __forceinline__ unsigned short f2bf(float f) {
    __hip_bfloat16 h = __float2bfloat16(f);
    return *reinterpret_cast<unsigned short*>(&h);
}

__device__ __forceinline__ float bf2f(unsigned short u) {
    unsigned int x = ((unsigned int)u) << 16;
    return *reinterpret_cast<float*>(&x);
}

// ---------- prep: nodef cvt, hist zero, all weight transposes, Wc/bc ----------
__global__ __launch_bounds__(256) void prep_all(
    const float* __restrict__ nodef,
    const float* __restrict__ W1m, unsigned short* __restrict__ w1t,
    const float* __restrict__ W1u, const float* __restrict__ W2u,
    const float* __restrict__ W2m, const float* __restrict__ b2m)
{
    int i = blockIdx.x * blockDim.x + threadIdx.x;
    if (i < BN * ND / 4) {
        float4 v = ((const float4*)nodef)[i];
        ushort4 o;
        o.x = f2bf(v.x); o.y = f2bf(v.y); o.z = f2bf(v.z); o.w = f2bf(v.w);
        ((ushort4*)g_nodef_bf)[i] = o;
    }
    if (i < BN) g_hist[i] = 0;
    if (i < K1 * HID) {
        int k = i % K1, n = i / K1;
        w1t[i] = f2bf(W1m[(size_t)k * HID + n]);
    }
    if (i < ND * HID) {
        int k = i % ND, n = i / ND;
        g_w1c[n * K1U + k] = f2bf(W1u[(size_t)k * HID + n]);
    }
    if (i < K2 * NOUT) {
        int k = i % K2, n = i / K2;
        g_w2ut[i] = f2bf(W2u[(size_t)k * NOUT + n]);
    }
    if (i < HID * HID) {
        int n = i & 255;
        int j = i >> 8;
        float a = 0.f;
        #pragma unroll 8
        for (int o = 0; o < HID; ++o)
            a += W2m[(size_t)j * HID + o] * W1u[(size_t)(128 + o) * HID + n];
        g_w1c[n * K1U + 128 + j] = f2bf(a);
    }
    if (i < HID) {
        float c = 0.f;
        #pragma unroll 8
        for (int o = 0; o < HID; ++o)
            c += b2m[o] * W1u[(size_t)(128 + o) * HID + i];
        g_bc[i] = c;
    }
}

// ---------- hist + agg zeroing (fused; 1250 blocks x 256 = 320000 threads) ----------
__global__ __launch_bounds__(256) void dst_hist(
    const int* __restrict__ eidx, float* __restrict__ agg)
{
    int e = blockIdx.x * blockDim.x + threadIdx.x;
    // zero agg: BN*HID/4 = 1,280,000 float4 = 4 per thread, coalesced
    float4 z = {0.f, 0.f, 0.f, 0.f};
    #pragma unroll
    for (int j = 0; j < 4; ++j)
        ((float4*)agg)[(size_t)j * BE + e] = z;
    if (e < BE) {
        int dst = eidx[2 * e + 1];
        int b   = e / E_EDGES;
        atomicAdd(&g_hist[b * N_NODES + dst], 1);
    }
}

// ---------- single-block exclusive scan (LDS-staged, coalesced) ----------
__global__ __launch_bounds__(1024, 1) void scan20k(int* __restrict__ offs)
{
    __shared__ int sh[BN];          // 80,000 B
    __shared__ int tots[1024];
    const int tid = threadIdx.x;
    for (int j = tid; j < BN; j += 1024) sh[j] = g_hist[j];   // coalesced in
    __syncthreads();
    const int base = tid * 20;
    int v[20];
    int s = 0;
    #pragma unroll
    for (int j = 0; j < 20; ++j) {
        int i = base + j;
        int h = (i < BN) ? sh[i] : 0;
        v[j] = s; s += h;
    }
    tots[tid] = s;
    __syncthreads();
    #pragma unroll
    for (int d = 1; d < 1024; d <<= 1) {
        int t = (tid >= d) ? tots[tid - d] : 0;
        __syncthreads();
        tots[tid] += t;
        __syncthreads();
    }
    int excl = tots[tid] - s;
    #pragma unroll
    for (int j = 0; j < 20; ++j) {
        int i = base + j;
        if (i < BN) sh[i] = excl + v[j];
    }
    __syncthreads();
    for (int j = tid; j < BN; j += 1024) offs[j] = sh[j];     // coalesced out
}

// ---------- pgemm + scatter (fused; 625 blocks x 512 = 320000 threads = BE) ----------
// scatter atomics issue first, drain under the MFMA work.
__global__ __launch_bounds__(512, 2) void pgemm_scatter(
    const unsigned short* __restrict__ w1t,
    const int* __restrict__ eidx,
    int* __restrict__ offs, int* __restrict__ perm)
{
    const int tid  = threadIdx.x;
    // ---- scatter: one edge per thread ----
    {
        int e   = blockIdx.x * 512 + tid;    // exact cover of BE
        int2 se = ((const int2*)eidx)[e];
        int b   = (e >= E_EDGES) ? 1 : 0;
        int pos = atomicAdd(&offs[b * N_NODES + se.y], 1);
        perm[pos] = e;
    }

    // ---- pgemm: g_Pb[n][0:512) = nodef_bf @ [W1m[0:128] | W1m[128:256]] ----
    const int wave = tid >> 6;
    const int lane = tid & 63;
    const int quad = lane >> 4;
    const int r16  = lane & 15;
    const int n0   = blockIdx.x * TMN;

    const int jb   = (wave & 3) * 64;              // col base within 256
    const int koff = (wave < 4) ? 0 : 128;         // W1m k-row offset
    const int cb   = (wave < 4) ? 0 : 256;         // output col-base add

    f32x4 acc[2][4];
    #pragma unroll
    for (int mt = 0; mt < 2; ++mt)
        #pragma unroll
        for (int nt = 0; nt < 4; ++nt)
            acc[mt][nt] = (f32x4){0.f, 0.f, 0.f, 0.f};

    for (int ks = 0; ks < ND / 32; ++ks) {
        bf16x8 wf[4], nf[2];
        #pragma unroll
        for (int nt = 0; nt < 4; ++nt)
            wf[nt] = *(const bf16x8*)&w1t[(size_t)(jb + nt * 16 + r16) * K1
                                          + koff + ks * 32 + quad * 8];
        #pragma unroll
        for (int mt = 0; mt < 2; ++mt)
            nf[mt] = *(const bf16x8*)&g_nodef_bf[(size_t)(n0 + mt * 16 + r16) * ND
                                                 + ks * 32 + quad * 8];
        #pragma unroll
        for (int mt = 0; mt < 2; ++mt)
            #pragma unroll
            for (int nt = 0; nt < 4; ++nt)
                acc[mt][nt] = __builtin_amdgcn_mfma_f32_16x16x32_bf16(
                    wf[nt], nf[mt], acc[mt][nt], 0, 0, 0);
    }

    #pragma unroll
    for (int nt = 0; nt < 4; ++nt) {
        int j0 = cb + jb + nt * 16 + quad * 4;
        #pragma unroll
        for (int mt = 0; mt < 2; ++mt) {
            int m = n0 + mt * 16 + r16;
            ushort4 o;
            o.x = f2bf(acc[mt][nt][0]); o.y = f2bf(acc[mt][nt][1]);
            o.z = f2bf(acc[mt][nt][2]); o.w = f2bf(acc[mt][nt][3]);
            *(ushort4*)&g_Pb[(size_t)m * 512 + j0] = o;
        }
    }
}

// ---------- edge MLP: early P-gather (latency spans staging+GEMM1); run-reduce h ----------
#define EK_SE   0
#define EK_SH   8192
#define EK_SMEM (8192 + TME * LDH * 2)   // 41,984

__global__ __launch_bounds__(512, 6) void edge_mlp_mfma(
    const int*            __restrict__ eidx,
    const float*          __restrict__ edgef,
    const int*            __restrict__ perm,
    const unsigned short* __restrict__ w1t,       // [256][320] bf16 n-major
    const float*          __restrict__ b1m,
    float* __restrict__ agg)                      // aggH: [BN][256] fp32
{
    __shared__ __align__(16) char smem[EK_SMEM];
    unsigned short* sE = (unsigned short*)(smem + EK_SE);
    unsigned short* sH = (unsigned short*)(smem + EK_SH);
    __shared__ int s_src[TME];
    __shared__ int s_dst[TME];
    __shared__ int s_eid[TME];

    const int tid  = threadIdx.x;
    const int wave = tid >> 6;
    const int lane = tid & 63;
    const int quad = lane >> 4;
    const int r16  = lane & 15;
    const int be0  = blockIdx.x * TME;

    if (tid < TME) {
        int eid = perm[be0 + tid];
        int b   = eid / E_EDGES;
        int2 se = ((const int2*)eidx)[eid];
        s_eid[tid] = eid;
        s_src[tid] = b * N_NODES + se.x;
        s_dst[tid] = b * N_NODES + se.y;
    }

    // GEMM1 weight A-frags (k-rows 256..319 of W1m) + biases: issue before barrier.
    const unsigned short* wB1 = w1t + (size_t)(wave * 32) * K1 + 256;
    bf16x8 wf00 = *(const bf16x8*)&wB1[(size_t)r16        * K1 + quad * 8];
    bf16x8 wf01 = *(const bf16x8*)&wB1[(size_t)r16        * K1 + 32 + quad * 8];
    bf16x8 wf10 = *(const bf16x8*)&wB1[(size_t)(16 + r16) * K1 + quad * 8];
    bf16x8 wf11 = *(const bf16x8*)&wB1[(size_t)(16 + r16) * K1 + 32 + quad * 8];
    float4 bb0 = *(const float4*)&b1m[wave * 32 + quad * 4];
    float4 bb1 = *(const float4*)&b1m[wave * 32 + 16 + quad * 4];

    __syncthreads();   // s_src/s_dst/s_eid visible

    // ---- issue P gathers EARLY: plain register loads stay in flight across
    //      the staging barrier and GEMM1 (~500+ cyc of cover). 32 VGPRs. ----
    ushort4 us[4][2], ud[4][2];
    #pragma unroll
    for (int mt = 0; mt < 4; ++mt) {
        int m = mt * 16 + r16;
        const unsigned short* pS = &g_Pb[(size_t)s_src[m] * 512];
        const unsigned short* pD = &g_Pb[(size_t)s_dst[m] * 512 + 256];
        #pragma unroll
        for (int nt = 0; nt < 2; ++nt) {
            int n0 = wave * 32 + nt * 16 + quad * 4;
            us[mt][nt] = *(const ushort4*)(pS + n0);
            ud[mt][nt] = *(const ushort4*)(pD + n0);
        }
    }

    // stage edge features fp32 -> bf16 panels: 2 x [64 rows x 32 k]
    {
        int row = tid >> 3;
        int c0  = (tid & 7) * 8;        // 0..56
        const float* fp = edgef + (size_t)s_eid[row] * ED + c0;
        float4 v0 = *(const float4*)fp;
        float4 v1 = *(const float4*)(fp + 4);
        ushort4 o0, o1;
        o0.x = f2bf(v0.x); o0.y = f2bf(v0.y); o0.z = f2bf(v0.z); o0.w = f2bf(v0.w);
        o1.x = f2bf(v1.x); o1.y = f2bf(v1.y); o1.z = f2bf(v1.z); o1.w = f2bf(v1.w);
        int p2 = c0 >> 5, kk = c0 & 31;
        *(ushort4*)&sE[p2 * 2048 + row * 32 + kk]     = o0;
        *(ushort4*)&sE[p2 * 2048 + row * 32 + kk + 4] = o1;
    }
    __syncthreads();

    f32x4 acc[4][2];
    #pragma unroll
    for (int mt = 0; mt < 4; ++mt)
        #pragma unroll
        for (int nt = 0; nt < 2; ++nt)
            acc[mt][nt] = (f32x4){0.f, 0.f, 0.f, 0.f};

    // ---- GEMM1: K=64 on edge features (A=weights, B=edge rows) ----
    #pragma unroll
    for (int mt = 0; mt < 4; ++mt) {
        bf16x8 e0 = *(const bf16x8*)&sE[(mt * 16 + r16) * 32 + quad * 8];
        bf16x8 e1 = *(const bf16x8*)&sE[2048 + (mt * 16 + r16) * 32 + quad * 8];
        acc[mt][0] = __builtin_amdgcn_mfma_f32_16x16x32_bf16(wf00, e0, acc[mt][0], 0, 0, 0);
        acc[mt][1] = __builtin_amdgcn_mfma_f32_16x16x32_bf16(wf10, e0, acc[mt][1], 0, 0, 0);
        acc[mt][0] = __builtin_amdgcn_mfma_f32_16x16x32_bf16(wf01, e1, acc[mt][0], 0, 0, 0);
        acc[mt][1] = __builtin_amdgcn_mfma_f32_16x16x32_bf16(wf11, e1, acc[mt][1], 0, 0, 0);
    }

    // ---- epilogue: + P[src] + P[dst] + b1, gelu -> sH (gathers already landed) ----
    #pragma unroll
    for (int mt = 0; mt < 4; ++mt) {
        int m = mt * 16 + r16;
        #pragma unroll
        for (int nt = 0; nt < 2; ++nt) {
            int n0 = wave * 32 + nt * 16 + quad * 4;
            float4 bb = nt ? bb1 : bb0;
            ushort4 u0 = us[mt][nt], u1 = ud[mt][nt];
            ushort4 o;
            o.x = f2bf(gelu_tanh(acc[mt][nt][0] + bf2f(u0.x) + bf2f(u1.x) + bb.x));
            o.y = f2bf(gelu_tanh(acc[mt][nt][1] + bf2f(u0.y) + bf2f(u1.y) + bb.y));
            o.z = f2bf(gelu_tanh(acc[mt][nt][2] + bf2f(u0.z) + bf2f(u1.z) + bb.z));
            o.w = f2bf(gelu_tanh(acc[mt][nt][3] + bf2f(u0.w) + bf2f(u1.w) + bb.w));
            *(ushort4*)&sH[m * LDH + n0] = o;
        }
    }
    __syncthreads();   // sH visible to all waves

    // ---- run-reduce h into agg (sorted dst -> compacted atomics) ----
    {
        const int cc = tid & 255;          // column
        const int r0 = (tid >> 8) * 32;    // row-half base
        int   cur  = s_dst[r0];
        float racc = 0.f;
        for (int mb = 0; mb < 32; mb += 8) {
            float v[8];
            #pragma unroll
            for (int j = 0; j < 8; ++j)
                v[j] = bf2f(sH[(r0 + mb + j) * LDH + cc]);
            #pragma unroll
            for (int j = 0; j < 8; ++j) {
                int d = s_dst[r0 + mb + j];
                if (d != cur) {
                    atomicAdd(&agg[(size_t)cur * HID + cc], racc);
                    cur = d; racc = v[j];
                } else {
                    racc += v[j];
                }
            }
        }
        atomicAdd(&agg[(size_t)cur * HID + cc], racc);
    }
}

// ---------- node MLP: 256 thr / 4 waves, TM=32 -> 625 blocks exactly ----------
// u_pre = nodef@W1u_a + aggH@Wc + hist*bc + b1u; out = gelu(u_pre)@W2u + b2u
__global__ __launch_bounds__(256, 4) void node_mlp_mfma(
    const float* __restrict__ agg,
    const float* __restrict__ b1u,
    const float* __restrict__ b2u,
    float* __restrict__ out)
{
    __shared__ __align__(16) unsigned short sH[TMN * LDH];   // 16,896 B

    const int tid  = threadIdx.x;
    const int wave = tid >> 6;     // 0..3: owns 64 L1-cols / 32 L2-cols
    const int lane = tid & 63;
    const int quad = lane >> 4;
    const int r16  = lane & 15;
    const int n0   = blockIdx.x * TMN;

    f32x4 acc[2][4];
    #pragma unroll
    for (int mt = 0; mt < 2; ++mt)
        #pragma unroll
        for (int nt = 0; nt < 4; ++nt)
            acc[mt][nt] = (f32x4){0.f, 0.f, 0.f, 0.f};

    // ---- L1 part A: k in [0,128) from g_nodef_bf ----
    for (int ks = 0; ks < 4; ++ks) {
        bf16x8 wf[4], nf[2];
        #pragma unroll
        for (int nt = 0; nt < 4; ++nt)
            wf[nt] = *(const bf16x8*)&g_w1c[(size_t)(wave * 64 + nt * 16 + r16) * K1U
                                            + ks * 32 + quad * 8];
        #pragma unroll
        for (int mt = 0; mt < 2; ++mt)
            nf[mt] = *(const bf16x8*)&g_nodef_bf[(size_t)(n0 + mt * 16 + r16) * ND
                                                 + ks * 32 + quad * 8];
        #pragma unroll
        for (int mt = 0; mt < 2; ++mt)
            #pragma unroll
            for (int nt = 0; nt < 4; ++nt)
                acc[mt][nt] = __builtin_amdgcn_mfma_f32_16x16x32_bf16(
                    wf[nt], nf[mt], acc[mt][nt], 0, 0, 0);
    }
    // ---- L1 part B: k in [128,384) = aggH @ Wc (fp32 -> bf16 in regs) ----
    for (int ks = 0; ks < 8; ++ks) {
        bf16x8 wf[4], nf[2];
        #pragma unroll
        for (int nt = 0; nt < 4; ++nt)
            wf[nt] = *(const bf16x8*)&g_w1c[(size_t)(wave * 64 + nt * 16 + r16) * K1U
                                            + (4 + ks) * 32 + quad * 8];
        #pragma unroll
        for (int mt = 0; mt < 2; ++mt) {
            const float* fp = &agg[(size_t)(n0 + mt * 16 + r16) * HID + ks * 32 + quad * 8];
            float4 v0 = *(const float4*)fp;
            float4 v1 = *(const float4*)(fp + 4);
            union { bf16x8 v; ushort4 u[2]; } cv;
            cv.u[0] = (ushort4){f2bf(v0.x), f2bf(v0.y), f2bf(v0.z), f2bf(v0.w)};
            cv.u[1] = (ushort4){f2bf(v1.x), f2bf(v1.y), f2bf(v1.z), f2bf(v1.w)};
            nf[mt] = cv.v;
        }
        #pragma unroll
        for (int mt = 0; mt < 2; ++mt)
            #pragma unroll
            for (int nt = 0; nt < 4; ++nt)
                acc[mt][nt] = __builtin_amdgcn_mfma_f32_16x16x32_bf16(
                    wf[nt], nf[mt], acc[mt][nt], 0, 0, 0);
    }

    // ---- L1 epilogue -> sH (ushort4 stores), bias = b1u + hist*bc ----
    #pragma unroll
    for (int nt = 0; nt < 4; ++nt) {
        int nn0 = wave * 64 + nt * 16 + quad * 4;
        float4 bb = *(const float4*)&b1u[nn0];
        float4 bc = *(const float4*)&g_bc[nn0];
        #pragma unroll
        for (int mt = 0; mt < 2; ++mt) {
            int row = n0 + mt * 16 + r16;
            float hv = (float)g_hist[row];
            int m = mt * 16 + r16;
            ushort4 o;
            o.x = f2bf(gelu_tanh(acc[mt][nt][0] + bb.x + hv * bc.x));
            o.y = f2bf(gelu_tanh(acc[mt][nt][1] + bb.y + hv * bc.y));
            o.z = f2bf(gelu_tanh(acc[mt][nt][2] + bb.z + hv * bc.z));
            o.w = f2bf(gelu_tanh(acc[mt][nt][3] + bb.w + hv * bc.w));
            *(ushort4*)&sH[m * LDH + nn0] = o;
        }
    }
    __syncthreads();

    f32x4 acc2[2][2];
    #pragma unroll
    for (int mt = 0; mt < 2; ++mt)
        #pragma unroll
        for (int nt = 0; nt < 2; ++nt)
            acc2[mt][nt] = (f32x4){0.f, 0.f, 0.f, 0.f};

    for (int ks = 0; ks < K2 / 32; ++ks) {
        bf16x8 wf2[2], hf[2];
        #pragma unroll
        for (int nt = 0; nt < 2; ++nt)
            wf2[nt] = *(const bf16x8*)&g_w2ut[(size_t)(wave * 32 + nt * 16 + r16) * K2
                                              + ks * 32 + quad * 8];
        #pragma unroll
        for (int mt = 0; mt < 2; ++mt)
            hf[mt] = *(const bf16x8*)&sH[(mt * 16 + r16) * LDH + ks * 32 + quad * 8];
        #pragma unroll
        for (int mt = 0; mt < 2; ++mt)
            #pragma unroll
            for (int nt = 0; nt < 2; ++nt)
                acc2[mt][nt] = __builtin_amdgcn_mfma_f32_16x16x32_bf16(
                    wf2[nt], hf[mt], acc2[mt][nt], 0, 0, 0);
    }

    // ---- L2 epilogue -> out (float4 stores) ----
    #pragma unroll
    for (int nt = 0; nt < 2; ++nt) {
        int j0 = wave * 32 + nt * 16 + quad * 4;
        float4 bb = *(const float4*)&b2u[j0];
        #pragma unroll
        for (int mt = 0; mt < 2; ++mt) {
            int row = n0 + mt * 16 + r16;
            float4 v = {acc2[mt][nt][0] + bb.x, acc2[mt][nt][1] + bb.y,
                        acc2[mt][nt][2] + bb.z, acc2[mt][nt][3] + bb.w};
            *(float4*)&out[(size_t)row * NOUT + j0] = v;
        }
    }
}

// ---------- launch ----------
// ws: aggH [0 .. 20,480,000). d_out stash (read only before node_mlp_mfma runs):
//   w1t  [5,120,000 .. 5,283,840)
//   offs [5,494,912 .. 5,574,912)
//   perm [5,574,912 .. 6,854,912)
// statics: g_Pb, g_nodef_bf, g_w1c, g_w2ut, g_bc, g_hist.
// 6 launches: prep_all | dst_hist(+agg-zero) | scan20k | pgemm_scatter | edge | node

extern "C" void kernel_launch(void* const* d_in, const int* in_sizes, int n_in,
                              void* d_out, int out_size, void* d_ws, size_t ws_size,
                              hipStream_t stream) {
    const float* nodef = (const float*)d_in[0];
    const int*   eidx  = (const int*)  d_in[1];
    const float* edgef = (const float*)d_in[2];
    const float* W1m   = (const float*)d_in[3];
    const float* b1m   = (const float*)d_in[4];
    const float* W2m   = (const float*)d_in[5];
    const float* b2m   = (const float*)d_in[6];
    const float* W1u   = (const float*)d_in[7];
    const float* b1u   = (const float*)d_in[8];
    const float* W2u   = (const float*)d_in[9];
    const float* b2u   = (const float*)d_in[10];
    float* out = (float*)d_out;

    char* wsb = (char*)d_ws;
    float* agg = (float*)wsb;

    char* ob = (char*)d_out;
    unsigned short* w1t  = (unsigned short*)(ob + 5120000);
    int* offs            = (int*)(ob + 5494912);
    int* perm            = (int*)(ob + 5574912);

    prep_all<<<(BN * ND / 4 + 255) / 256, 256, 0, stream>>>(
        nodef, W1m, w1t, W1u, W2u, W2m, b2m);

    dst_hist<<<BE / 256, 256, 0, stream>>>(eidx, agg);
    scan20k<<<1, 1024, 0, stream>>>(offs);

    pgemm_scatter<<<BN / TMN, 512, 0, stream>>>(w1t, eidx, offs, perm);

    edge_mlp_mfma<<<BE / TME, 512, 0, stream>>>(
        eidx, edgef, perm, w1t, b1m, agg);

    node_mlp_mfma<<<BN / TMN, 256, 0, stream>>>(agg, b1u, b2u, out);
}

// Round 8
// 340.254 us; speedup vs baseline: 1.1578x; 1.1578x over previous
//
#include <hip/hip_runtime.h>
#include <hip/hip_bf16.h>
#include <math.h>

#define BATCH   2
#define N_NODES 10000
#define E_EDGES 160000
#define BN      (BATCH * N_NODES)       // 20000
#define BE      (BATCH * E_EDGES)       // 320000
#define ND      128
#define ED      64
#define HID     256
#define K1      320   // 2*ND + ED
#define K2      256
#define K1U     384   // ND + HID
#define NOUT    128
#define TMN     32    // node/pgemm rows per block (20000 = 625*32, exact)
#define TME     64    // edge-kernel rows per block
#define LDH     264   // H stride (bf16), 256+8

typedef __attribute__((ext_vector_type(8))) short bf16x8;
typedef __attribute__((ext_vector_type(4))) float f32x4;

// ---------- static device buffers ----------
__device__ unsigned short g_Pb[(size_t)BN * 512];       // bf16: [n][0:256)=src-part, [256:512)=dst-part
__device__ unsigned short g_nodef_bf[(size_t)BN * ND];  // bf16 node features
__device__ unsigned short g_w1c[HID * K1U];             // node L1 weights n-major bf16:
                                                        //   cols [0,128)  = W1u[0:128]^T
                                                        //   cols [128,384)= (W2m @ W1u[128:384])^T
__device__ unsigned short g_w2ut[K2 * NOUT];            // node L2 weights, n-major bf16
__device__ float          g_bc[HID];                    // b2m @ W1u[128:384]
__device__ int            g_hist[BN];                   // per-dst edge counts

// fast tanh-gelu: tanh(u) = 1 - 2/(exp(2u)+1); both tails saturate correctly.
__device__ __forceinline__ float gelu_tanh(float x) {
    float u = 0.7978845608028654f * (x + 0.044715f * x * x * x);
    float e = __expf(2.0f * u);
    float t = 1.0f - 2.0f * __builtin_amdgcn_rcpf(e + 1.0f);
    return 0.5f * x * (1.0f + t);
}

__device__ __forceinline__ unsigned short f2bf(float f) {
    __hip_bfloat16 h = __float2bfloat16(f);
    return *reinterpret_cast<unsigned short*>(&h);
}

__device__ __forceinline__ float bf2f(unsigned short u) {
    unsigned int x = ((unsigned int)u) << 16;
    return *reinterpret_cast<float*>(&x);
}

// ---------- prep: nodef cvt, hist zero, all weight transposes, Wc/bc ----------
__global__ __launch_bounds__(256) void prep_all(
    const float* __restrict__ nodef,
    const float* __restrict__ W1m, unsigned short* __restrict__ w1t,
    const float* __restrict__ W1u, const float* __restrict__ W2u,
    const float* __restrict__ W2m, const float* __restrict__ b2m)
{
    int i = blockIdx.x * blockDim.x + threadIdx.x;
    if (i < BN * ND / 4) {
        float4 v = ((const float4*)nodef)[i];
        ushort4 o;
        o.x = f2bf(v.x); o.y = f2bf(v.y); o.z = f2bf(v.z); o.w = f2bf(v.w);
        ((ushort4*)g_nodef_bf)[i] = o;
    }
    if (i < BN) g_hist[i] = 0;
    if (i < K1 * HID) {
        int k = i % K1, n = i / K1;
        w1t[i] = f2bf(W1m[(size_t)k * HID + n]);
    }
    if (i < ND * HID) {
        int k = i % ND, n = i / ND;
        g_w1c[n * K1U + k] = f2bf(W1u[(size_t)k * HID + n]);
    }
    if (i < K2 * NOUT) {
        int k = i % K2, n = i / K2;
        g_w2ut[i] = f2bf(W2u[(size_t)k * NOUT + n]);
    }
    if (i < HID * HID) {
        int n = i & 255;
        int j = i >> 8;
        float a = 0.f;
        #pragma unroll 8
        for (int o = 0; o < HID; ++o)
            a += W2m[(size_t)j * HID + o] * W1u[(size_t)(128 + o) * HID + n];
        g_w1c[n * K1U + 128 + j] = f2bf(a);
    }
    if (i < HID) {
        float c = 0.f;
        #pragma unroll 8
        for (int o = 0; o < HID; ++o)
            c += b2m[o] * W1u[(size_t)(128 + o) * HID + i];
        g_bc[i] = c;
    }
}

// ---------- hist + agg zeroing (fused; 1250 blocks x 256 = 320000 threads) ----------
__global__ __launch_bounds__(256) void dst_hist(
    const int* __restrict__ eidx, float* __restrict__ agg)
{
    int e = blockIdx.x * blockDim.x + threadIdx.x;
    // zero agg: BN*HID/4 = 1,280,000 float4 = 4 per thread, coalesced
    float4 z = {0.f, 0.f, 0.f, 0.f};
    #pragma unroll
    for (int j = 0; j < 4; ++j)
        ((float4*)agg)[(size_t)j * BE + e] = z;
    if (e < BE) {
        int dst = eidx[2 * e + 1];
        int b   = e / E_EDGES;
        atomicAdd(&g_hist[b * N_NODES + dst], 1);
    }
}

// ---------- single-block exclusive scan (LDS-staged, coalesced) ----------
__global__ __launch_bounds__(1024, 1) void scan20k(int* __restrict__ offs)
{
    __shared__ int sh[BN];          // 80,000 B
    __shared__ int tots[1024];
    const int tid = threadIdx.x;
    for (int j = tid; j < BN; j += 1024) sh[j] = g_hist[j];   // coalesced in
    __syncthreads();
    const int base = tid * 20;
    int v[20];
    int s = 0;
    #pragma unroll
    for (int j = 0; j < 20; ++j) {
        int i = base + j;
        int h = (i < BN) ? sh[i] : 0;
        v[j] = s; s += h;
    }
    tots[tid] = s;
    __syncthreads();
    #pragma unroll
    for (int d = 1; d < 1024; d <<= 1) {
        int t = (tid >= d) ? tots[tid - d] : 0;
        __syncthreads();
        tots[tid] += t;
        __syncthreads();
    }
    int excl = tots[tid] - s;
    #pragma unroll
    for (int j = 0; j < 20; ++j) {
        int i = base + j;
        if (i < BN) sh[i] = excl + v[j];
    }
    __syncthreads();
    for (int j = tid; j < BN; j += 1024) offs[j] = sh[j];     // coalesced out
}

// ---------- pgemm + scatter (fused; 625 blocks x 512 = 320000 threads = BE) ----------
// scatter atomics issue first, drain under the MFMA work.
__global__ __launch_bounds__(512, 2) void pgemm_scatter(
    const unsigned short* __restrict__ w1t,
    const int* __restrict__ eidx,
    int* __restrict__ offs, int* __restrict__ perm)
{
    const int tid  = threadIdx.x;
    // ---- scatter: one edge per thread ----
    {
        int e   = blockIdx.x * 512 + tid;    // exact cover of BE
        int2 se = ((const int2*)eidx)[e];
        int b   = (e >= E_EDGES) ? 1 : 0;
        int pos = atomicAdd(&offs[b * N_NODES + se.y], 1);
        perm[pos] = e;
    }

    // ---- pgemm: g_Pb[n][0:512) = nodef_bf @ [W1m[0:128] | W1m[128:256]] ----
    const int wave = tid >> 6;
    const int lane = tid & 63;
    const int quad = lane >> 4;
    const int r16  = lane & 15;
    const int n0   = blockIdx.x * TMN;

    const int jb   = (wave & 3) * 64;              // col base within 256
    const int koff = (wave < 4) ? 0 : 128;         // W1m k-row offset
    const int cb   = (wave < 4) ? 0 : 256;         // output col-base add

    f32x4 acc[2][4];
    #pragma unroll
    for (int mt = 0; mt < 2; ++mt)
        #pragma unroll
        for (int nt = 0; nt < 4; ++nt)
            acc[mt][nt] = (f32x4){0.f, 0.f, 0.f, 0.f};

    for (int ks = 0; ks < ND / 32; ++ks) {
        bf16x8 wf[4], nf[2];
        #pragma unroll
        for (int nt = 0; nt < 4; ++nt)
            wf[nt] = *(const bf16x8*)&w1t[(size_t)(jb + nt * 16 + r16) * K1
                                          + koff + ks * 32 + quad * 8];
        #pragma unroll
        for (int mt = 0; mt < 2; ++mt)
            nf[mt] = *(const bf16x8*)&g_nodef_bf[(size_t)(n0 + mt * 16 + r16) * ND
                                                 + ks * 32 + quad * 8];
        #pragma unroll
        for (int mt = 0; mt < 2; ++mt)
            #pragma unroll
            for (int nt = 0; nt < 4; ++nt)
                acc[mt][nt] = __builtin_amdgcn_mfma_f32_16x16x32_bf16(
                    wf[nt], nf[mt], acc[mt][nt], 0, 0, 0);
    }

    #pragma unroll
    for (int nt = 0; nt < 4; ++nt) {
        int j0 = cb + jb + nt * 16 + quad * 4;
        #pragma unroll
        for (int mt = 0; mt < 2; ++mt) {
            int m = n0 + mt * 16 + r16;
            ushort4 o;
            o.x = f2bf(acc[mt][nt][0]); o.y = f2bf(acc[mt][nt][1]);
            o.z = f2bf(acc[mt][nt][2]); o.w = f2bf(acc[mt][nt][3]);
            *(ushort4*)&g_Pb[(size_t)m * 512 + j0] = o;
        }
    }
}

// ---------- edge MLP (round-6 proven form: gather in epilogue, no spill) ----------
#define EK_SE   0
#define EK_SH   8192
#define EK_SMEM (8192 + TME * LDH * 2)   // 41,984

__global__ __launch_bounds__(512, 6) void edge_mlp_mfma(
    const int*            __restrict__ eidx,
    const float*          __restrict__ edgef,
    const int*            __restrict__ perm,
    const unsigned short* __restrict__ w1t,       // [256][320] bf16 n-major
    const float*          __restrict__ b1m,
    float* __restrict__ agg)                      // aggH: [BN][256] fp32
{
    __shared__ __align__(16) char smem[EK_SMEM];
    unsigned short* sE = (unsigned short*)(smem + EK_SE);
    unsigned short* sH = (unsigned short*)(smem + EK_SH);
    __shared__ int s_src[TME];
    __shared__ int s_dst[TME];
    __shared__ int s_eid[TME];

    const int tid  = threadIdx.x;
    const int wave = tid >> 6;
    const int lane = tid & 63;
    const int quad = lane >> 4;
    const int r16  = lane & 15;
    const int be0  = blockIdx.x * TME;

    if (tid < TME) {
        int eid = perm[be0 + tid];
        int b   = eid / E_EDGES;
        int2 se = ((const int2*)eidx)[eid];
        s_eid[tid] = eid;
        s_src[tid] = b * N_NODES + se.x;
        s_dst[tid] = b * N_NODES + se.y;
    }

    // GEMM1 weight A-frags (k-rows 256..319 of W1m): issue early, overlap staging.
    const unsigned short* wB1 = w1t + (size_t)(wave * 32) * K1 + 256;
    bf16x8 wf00 = *(const bf16x8*)&wB1[(size_t)r16        * K1 + quad * 8];
    bf16x8 wf01 = *(const bf16x8*)&wB1[(size_t)r16        * K1 + 32 + quad * 8];
    bf16x8 wf10 = *(const bf16x8*)&wB1[(size_t)(16 + r16) * K1 + quad * 8];
    bf16x8 wf11 = *(const bf16x8*)&wB1[(size_t)(16 + r16) * K1 + 32 + quad * 8];

    __syncthreads();   // s_src/s_dst/s_eid visible

    // stage edge features fp32 -> bf16 panels: 2 x [64 rows x 32 k]
    {
        int row = tid >> 3;
        int c0  = (tid & 7) * 8;        // 0..56
        const float* fp = edgef + (size_t)s_eid[row] * ED + c0;
        float4 v0 = *(const float4*)fp;
        float4 v1 = *(const float4*)(fp + 4);
        ushort4 o0, o1;
        o0.x = f2bf(v0.x); o0.y = f2bf(v0.y); o0.z = f2bf(v0.z); o0.w = f2bf(v0.w);
        o1.x = f2bf(v1.x); o1.y = f2bf(v1.y); o1.z = f2bf(v1.z); o1.w = f2bf(v1.w);
        int p2 = c0 >> 5, kk = c0 & 31;
        *(ushort4*)&sE[p2 * 2048 + row * 32 + kk]     = o0;
        *(ushort4*)&sE[p2 * 2048 + row * 32 + kk + 4] = o1;
    }
    __syncthreads();

    f32x4 acc[4][2];
    #pragma unroll
    for (int mt = 0; mt < 4; ++mt)
        #pragma unroll
        for (int nt = 0; nt < 2; ++nt)
            acc[mt][nt] = (f32x4){0.f, 0.f, 0.f, 0.f};

    // ---- GEMM1: K=64 on edge features (A=weights, B=edge rows) ----
    #pragma unroll
    for (int mt = 0; mt < 4; ++mt) {
        bf16x8 e0 = *(const bf16x8*)&sE[(mt * 16 + r16) * 32 + quad * 8];
        bf16x8 e1 = *(const bf16x8*)&sE[2048 + (mt * 16 + r16) * 32 + quad * 8];
        acc[mt][0] = __builtin_amdgcn_mfma_f32_16x16x32_bf16(wf00, e0, acc[mt][0], 0, 0, 0);
        acc[mt][1] = __builtin_amdgcn_mfma_f32_16x16x32_bf16(wf10, e0, acc[mt][1], 0, 0, 0);
        acc[mt][0] = __builtin_amdgcn_mfma_f32_16x16x32_bf16(wf01, e1, acc[mt][0], 0, 0, 0);
        acc[mt][1] = __builtin_amdgcn_mfma_f32_16x16x32_bf16(wf11, e1, acc[mt][1], 0, 0, 0);
    }

    // ---- gather-add epilogue: + P[src] + P[dst] + b1, gelu -> sH (bf16 P, ushort4) ----
    {
        float4 bb[2];
        bb[0] = *(const float4*)&b1m[wave * 32 + quad * 4];
        bb[1] = *(const float4*)&b1m[wave * 32 + 16 + quad * 4];
        #pragma unroll
        for (int mt = 0; mt < 4; ++mt) {
            int m = mt * 16 + r16;
            const unsigned short* pS = &g_Pb[(size_t)s_src[m] * 512];
            const unsigned short* pD = &g_Pb[(size_t)s_dst[m] * 512 + 256];
            #pragma unroll
            for (int nt = 0; nt < 2; ++nt) {
                int n0 = wave * 32 + nt * 16 + quad * 4;
                ushort4 us = *(const ushort4*)(pS + n0);
                ushort4 ud = *(const ushort4*)(pD + n0);
                ushort4 o;
                o.x = f2bf(gelu_tanh(acc[mt][nt][0] + bf2f(us.x) + bf2f(ud.x) + bb[nt].x));
                o.y = f2bf(gelu_tanh(acc[mt][nt][1] + bf2f(us.y) + bf2f(ud.y) + bb[nt].y));
                o.z = f2bf(gelu_tanh(acc[mt][nt][2] + bf2f(us.z) + bf2f(ud.z) + bb[nt].z));
                o.w = f2bf(gelu_tanh(acc[mt][nt][3] + bf2f(us.w) + bf2f(ud.w) + bb[nt].w));
                *(ushort4*)&sH[m * LDH + n0] = o;
            }
        }
    }
    __syncthreads();   // sH visible to all waves

    // ---- run-reduce h into agg (sorted dst -> compacted atomics) ----
    {
        const int cc = tid & 255;          // column
        const int r0 = (tid >> 8) * 32;    // row-half base
        int   cur  = s_dst[r0];
        float racc = 0.f;
        for (int mb = 0; mb < 32; mb += 8) {
            float v[8];
            #pragma unroll
            for (int j = 0; j < 8; ++j)
                v[j] = bf2f(sH[(r0 + mb + j) * LDH + cc]);
            #pragma unroll
            for (int j = 0; j < 8; ++j) {
                int d = s_dst[r0 + mb + j];
                if (d != cur) {
                    atomicAdd(&agg[(size_t)cur * HID + cc], racc);
                    cur = d; racc = v[j];
                } else {
                    racc += v[j];
                }
            }
        }
        atomicAdd(&agg[(size_t)cur * HID + cc], racc);
    }
}

// ---------- node MLP: 256 thr / 4 waves, TM=32 -> 625 blocks exactly ----------
// u_pre = nodef@W1u_a + aggH@Wc + hist*bc + b1u; out = gelu(u_pre)@W2u + b2u
__global__ __launch_bounds__(256, 4) void node_mlp_mfma(
    const float* __restrict__ agg,
    const float* __restrict__ b1u,
    const float* __restrict__ b2u,
    float* __restrict__ out)
{
    __shared__ __align__(16) unsigned short sH[TMN * LDH];   // 16,896 B

    const int tid  = threadIdx.x;
    const int wave = tid >> 6;     // 0..3: owns 64 L1-cols / 32 L2-cols
    const int lane = tid & 63;
    const int quad = lane >> 4;
    const int r16  = lane & 15;
    const int n0   = blockIdx.x * TMN;

    f32x4 acc[2][4];
    #pragma unroll
    for (int mt = 0; mt < 2; ++mt)
        #pragma unroll
        for (int nt = 0; nt < 4; ++nt)
            acc[mt][nt] = (f32x4){0.f, 0.f, 0.f, 0.f};

    // ---- L1 part A: k in [0,128) from g_nodef_bf ----
    for (int ks = 0; ks < 4; ++ks) {
        bf16x8 wf[4], nf[2];
        #pragma unroll
        for (int nt = 0; nt < 4; ++nt)
            wf[nt] = *(const bf16x8*)&g_w1c[(size_t)(wave * 64 + nt * 16 + r16) * K1U
                                            + ks * 32 + quad * 8];
        #pragma unroll
        for (int mt = 0; mt < 2; ++mt)
            nf[mt] = *(const bf16x8*)&g_nodef_bf[(size_t)(n0 + mt * 16 + r16) * ND
                                                 + ks * 32 + quad * 8];
        #pragma unroll
        for (int mt = 0; mt < 2; ++mt)
            #pragma unroll
            for (int nt = 0; nt < 4; ++nt)
                acc[mt][nt] = __builtin_amdgcn_mfma_f32_16x16x32_bf16(
                    wf[nt], nf[mt], acc[mt][nt], 0, 0, 0);
    }
    // ---- L1 part B: k in [128,384) = aggH @ Wc (fp32 -> bf16 in regs) ----
    for (int ks = 0; ks < 8; ++ks) {
        bf16x8 wf[4], nf[2];
        #pragma unroll
        for (int nt = 0; nt < 4; ++nt)
            wf[nt] = *(const bf16x8*)&g_w1c[(size_t)(wave * 64 + nt * 16 + r16) * K1U
                                            + (4 + ks) * 32 + quad * 8];
        #pragma unroll
        for (int mt = 0; mt < 2; ++mt) {
            const float* fp = &agg[(size_t)(n0 + mt * 16 + r16) * HID + ks * 32 + quad * 8];
            float4 v0 = *(const float4*)fp;
            float4 v1 = *(const float4*)(fp + 4);
            union { bf16x8 v; ushort4 u[2]; } cv;
            cv.u[0] = (ushort4){f2bf(v0.x), f2bf(v0.y), f2bf(v0.z), f2bf(v0.w)};
            cv.u[1] = (ushort4){f2bf(v1.x), f2bf(v1.y), f2bf(v1.z), f2bf(v1.w)};
            nf[mt] = cv.v;
        }
        #pragma unroll
        for (int mt = 0; mt < 2; ++mt)
            #pragma unroll
            for (int nt = 0; nt < 4; ++nt)
                acc[mt][nt] = __builtin_amdgcn_mfma_f32_16x16x32_bf16(
                    wf[nt], nf[mt], acc[mt][nt], 0, 0, 0);
    }

    // ---- L1 epilogue -> sH (ushort4 stores), bias = b1u + hist*bc ----
    #pragma unroll
    for (int nt = 0; nt < 4; ++nt) {
        int nn0 = wave * 64 + nt * 16 + quad * 4;
        float4 bb = *(const float4*)&b1u[nn0];
        float4 bc = *(const float4*)&g_bc[nn0];
        #pragma unroll
        for (int mt = 0; mt < 2; ++mt) {
            int row = n0 + mt * 16 + r16;
            float hv = (float)g_hist[row];
            int m = mt * 16 + r16;
            ushort4 o;
            o.x = f2bf(gelu_tanh(acc[mt][nt][0] + bb.x + hv * bc.x));
            o.y = f2bf(gelu_tanh(acc[mt][nt][1] + bb.y + hv * bc.y));
            o.z = f2bf(gelu_tanh(acc[mt][nt][2] + bb.z + hv * bc.z));
            o.w = f2bf(gelu_tanh(acc[mt][nt][3] + bb.w + hv * bc.w));
            *(ushort4*)&sH[m * LDH + nn0] = o;
        }
    }
    __syncthreads();

    f32x4 acc2[2][2];
    #pragma unroll
    for (int mt = 0; mt < 2; ++mt)
        #pragma unroll
        for (int nt = 0; nt < 2; ++nt)
            acc2[mt][nt] = (f32x4){0.f, 0.f, 0.f, 0.f};

    for (int ks = 0; ks < K2 / 32; ++ks) {
        bf16x8 wf2[2], hf[2];
        #pragma unroll
        for (int nt = 0; nt < 2; ++nt)
            wf2[nt] = *(const bf16x8*)&g_w2ut[(size_t)(wave * 32 + nt * 16 + r16) * K2
                                              + ks * 32 + quad * 8];
        #pragma unroll
        for (int mt = 0; mt < 2; ++mt)
            hf[mt] = *(const bf16x8*)&sH[(mt * 16 + r16) * LDH + ks * 32 + quad * 8];
        #pragma unroll
        for (int mt = 0; mt < 2; ++mt)
            #pragma unroll
            for (int nt = 0; nt < 2; ++nt)
                acc2[mt][nt] = __builtin_amdgcn_mfma_f32_16x16x32_bf16(
                    wf2[nt], hf[mt], acc2[mt][nt], 0, 0, 0);
    }

    // ---- L2 epilogue -> out (float4 stores) ----
    #pragma unroll
    for (int nt = 0; nt < 2; ++nt) {
        int j0 = wave * 32 + nt * 16 + quad * 4;
        float4 bb = *(const float4*)&b2u[j0];
        #pragma unroll
        for (int mt = 0; mt < 2; ++mt) {
            int row = n0 + mt * 16 + r16;
            float4 v = {acc2[mt][nt][0] + bb.x, acc2[mt][nt][1] + bb.y,
                        acc2[mt][nt][2] + bb.z, acc2[mt][nt][3] + bb.w};
            *(float4*)&out[(size_t)row * NOUT + j0] = v;
        }
    }
}

// ---------- launch ----------
// ws: aggH [0 .. 20,480,000). d_out stash (read only before node_mlp_mfma runs):
//   w1t  [5,120,000 .. 5,283,840)
//   offs [5,494,912 .. 5,574,912)
//   perm [5,574,912 .. 6,854,912)
// statics: g_Pb, g_nodef_bf, g_w1c, g_w2ut, g_bc, g_hist.
// 6 launches: prep_all | dst_hist(+agg-zero) | scan20k | pgemm_scatter | edge | node

extern "C" void kernel_launch(void* const* d_in, const int* in_sizes, int n_in,
                              void* d_out, int out_size, void* d_ws, size_t ws_size,
                              hipStream_t stream) {
    const float* nodef = (const float*)d_in[0];
    const int*   eidx  = (const int*)  d_in[1];
    const float* edgef = (const float*)d_in[2];
    const float* W1m   = (const float*)d_in[3];
    const float* b1m   = (const float*)d_in[4];
    const float* W2m   = (const float*)d_in[5];
    const float* b2m   = (const float*)d_in[6];
    const float* W1u   = (const float*)d_in[7];
    const float* b1u   = (const float*)d_in[8];
    const float* W2u   = (const float*)d_in[9];
    const float* b2u   = (const float*)d_in[10];
    float* out = (float*)d_out;

    char* wsb = (char*)d_ws;
    float* agg = (float*)wsb;

    char* ob = (char*)d_out;
    unsigned short* w1t  = (unsigned short*)(ob + 5120000);
    int* offs            = (int*)(ob + 5494912);
    int* perm            = (int*)(ob + 5574912);

    prep_all<<<(BN * ND / 4 + 255) / 256, 256, 0, stream>>>(
        nodef, W1m, w1t, W1u, W2u, W2m, b2m);

    dst_hist<<<BE / 256, 256, 0, stream>>>(eidx, agg);
    scan20k<<<1, 1024, 0, stream>>>(offs);

    pgemm_scatter<<<BN / TMN, 512, 0, stream>>>(w1t, eidx, offs, perm);

    edge_mlp_mfma<<<BE / TME, 512, 0, stream>>>(
        eidx, edgef, perm, w1t, b1m, agg);

    node_mlp_mfma<<<BN / TMN, 256, 0, stream>>>(agg, b1u, b2u, out);
}

// Round 9
// 331.465 us; speedup vs baseline: 1.1885x; 1.0265x over previous
//
#include <hip/hip_runtime.h>
#include <hip/hip_bf16.h>
#include <math.h>

#define BATCH   2
#define N_NODES 10000
#define E_EDGES 160000
#define BN      (BATCH * N_NODES)       // 20000
#define BE      (BATCH * E_EDGES)       // 320000
#define ND      128
#define ED      64
#define HID     256
#define K1      320   // 2*ND + ED
#define K2      256
#define K1U     384   // ND + HID
#define NOUT    128
#define TMN     32    // node/pgemm rows per block (20000 = 625*32, exact)
#define TME     64    // edge-kernel rows per block
#define LDH     264   // H stride (bf16), 256+8

typedef __attribute__((ext_vector_type(8))) short bf16x8;
typedef __attribute__((ext_vector_type(4))) float f32x4;

// ---------- static device buffers ----------
__device__ unsigned short g_Pb[(size_t)BN * 512];       // bf16: [n][0:256)=src-part, [256:512)=dst-part
__device__ unsigned short g_nodef_bf[(size_t)BN * ND];  // bf16 node features
__device__ unsigned short g_w1c[HID * K1U];             // node L1 weights n-major bf16:
                                                        //   cols [0,128)  = W1u[0:128]^T
                                                        //   cols [128,384)= (W2m @ W1u[128:384])^T
__device__ unsigned short g_w2ut[K2 * NOUT];            // node L2 weights, n-major bf16
__device__ float          g_bc[HID];                    // b2m @ W1u[128:384]
__device__ int            g_hist[BN];                   // per-dst counts; zero at load,
                                                        // re-zeroed by scan20k each iter
__device__ int            g_offs[BN];                   // excl prefix; post-scatter = incl prefix

// fast tanh-gelu: tanh(u) = 1 - 2/(exp(2u)+1); both tails saturate correctly.
__device__ __forceinline__ float gelu_tanh(float x) {
    float u = 0.7978845608028654f * (x + 0.044715f * x * x * x);
    float e = __expf(2.0f * u);
    float t = 1.0f - 2.0f * __builtin_amdgcn_rcpf(e + 1.0f);
    return 0.5f * x * (1.0f + t);
}

__device__ __forceinline__ unsigned short f2bf(float f) {
    __hip_bfloat16 h = __float2bfloat16(f);
    return *reinterpret_cast<unsigned short*>(&h);
}

__device__ __forceinline__ float bf2f(unsigned short u) {
    unsigned int x = ((unsigned int)u) << 16;
    return *reinterpret_cast<float*>(&x);
}

// ---------- merged prep: nodef cvt, agg zero, dst hist, weight transposes, Wc/bc ----------
// grid 2500 x 256 = 640,000 threads = BN*ND/4 exactly.
// g_hist arrives zeroed (module load / previous iteration's scan20k).
__global__ __launch_bounds__(256) void prep_hist(
    const float* __restrict__ nodef, const int* __restrict__ eidx,
    float* __restrict__ agg,
    const float* __restrict__ W1m, unsigned short* __restrict__ w1t,
    const float* __restrict__ W1u, const float* __restrict__ W2u,
    const float* __restrict__ W2m, const float* __restrict__ b2m)
{
    int i = blockIdx.x * blockDim.x + threadIdx.x;
    // nodef fp32 -> bf16 (exact cover)
    {
        float4 v = ((const float4*)nodef)[i];
        ushort4 o;
        o.x = f2bf(v.x); o.y = f2bf(v.y); o.z = f2bf(v.z); o.w = f2bf(v.w);
        ((ushort4*)g_nodef_bf)[i] = o;
    }
    // agg zero: 1,280,000 float4, 2 per thread (exact cover)
    {
        float4 z = {0.f, 0.f, 0.f, 0.f};
        ((float4*)agg)[i] = z;
        ((float4*)agg)[i + 640000] = z;
    }
    // dst histogram
    if (i < BE) {
        int dst = eidx[2 * i + 1];
        int b   = i / E_EDGES;
        atomicAdd(&g_hist[b * N_NODES + dst], 1);
    }
    // weight transposes
    if (i < K1 * HID) {
        int k = i % K1, n = i / K1;
        w1t[i] = f2bf(W1m[(size_t)k * HID + n]);
    }
    if (i < ND * HID) {
        int k = i % ND, n = i / ND;
        g_w1c[n * K1U + k] = f2bf(W1u[(size_t)k * HID + n]);
    }
    if (i < K2 * NOUT) {
        int k = i % K2, n = i / K2;
        g_w2ut[i] = f2bf(W2u[(size_t)k * NOUT + n]);
    }
    if (i < HID * HID) {
        int n = i & 255;
        int j = i >> 8;
        float a = 0.f;
        #pragma unroll 8
        for (int o = 0; o < HID; ++o)
            a += W2m[(size_t)j * HID + o] * W1u[(size_t)(128 + o) * HID + n];
        g_w1c[n * K1U + 128 + j] = f2bf(a);
    }
    if (i < HID) {
        float c = 0.f;
        #pragma unroll 8
        for (int o = 0; o < HID; ++o)
            c += b2m[o] * W1u[(size_t)(128 + o) * HID + i];
        g_bc[i] = c;
    }
}

// ---------- single-block exclusive scan (LDS-staged, coalesced) + g_hist rezero ----------
__global__ __launch_bounds__(1024, 1) void scan20k()
{
    __shared__ int sh[BN];          // 80,000 B
    __shared__ int tots[1024];
    const int tid = threadIdx.x;
    for (int j = tid; j < BN; j += 1024) {
        sh[j] = g_hist[j];          // coalesced in
        g_hist[j] = 0;              // rezero for next iteration (same thread, same addr)
    }
    __syncthreads();
    const int base = tid * 20;
    int v[20];
    int s = 0;
    #pragma unroll
    for (int j = 0; j < 20; ++j) {
        int i = base + j;
        int h = (i < BN) ? sh[i] : 0;
        v[j] = s; s += h;
    }
    tots[tid] = s;
    __syncthreads();
    #pragma unroll
    for (int d = 1; d < 1024; d <<= 1) {
        int t = (tid >= d) ? tots[tid - d] : 0;
        __syncthreads();
        tots[tid] += t;
        __syncthreads();
    }
    int excl = tots[tid] - s;
    #pragma unroll
    for (int j = 0; j < 20; ++j) {
        int i = base + j;
        if (i < BN) sh[i] = excl + v[j];
    }
    __syncthreads();
    for (int j = tid; j < BN; j += 1024) g_offs[j] = sh[j];   // coalesced out
}

// ---------- pgemm + scatter (fused; 625 blocks x 512 = 320000 threads = BE) ----------
// scatter atomics issue first, drain under the MFMA work.
// NOTE: scatter mutates g_offs -> afterwards g_offs[i] = inclusive prefix (used by node_mlp).
__global__ __launch_bounds__(512, 2) void pgemm_scatter(
    const unsigned short* __restrict__ w1t,
    const int* __restrict__ eidx,
    int* __restrict__ perm)
{
    const int tid  = threadIdx.x;
    // ---- scatter: one edge per thread ----
    {
        int e   = blockIdx.x * 512 + tid;    // exact cover of BE
        int2 se = ((const int2*)eidx)[e];
        int b   = (e >= E_EDGES) ? 1 : 0;
        int pos = atomicAdd(&g_offs[b * N_NODES + se.y], 1);
        perm[pos] = e;
    }

    // ---- pgemm: g_Pb[n][0:512) = nodef_bf @ [W1m[0:128] | W1m[128:256]] ----
    const int wave = tid >> 6;
    const int lane = tid & 63;
    const int quad = lane >> 4;
    const int r16  = lane & 15;
    const int n0   = blockIdx.x * TMN;

    const int jb   = (wave & 3) * 64;              // col base within 256
    const int koff = (wave < 4) ? 0 : 128;         // W1m k-row offset
    const int cb   = (wave < 4) ? 0 : 256;         // output col-base add

    f32x4 acc[2][4];
    #pragma unroll
    for (int mt = 0; mt < 2; ++mt)
        #pragma unroll
        for (int nt = 0; nt < 4; ++nt)
            acc[mt][nt] = (f32x4){0.f, 0.f, 0.f, 0.f};

    for (int ks = 0; ks < ND / 32; ++ks) {
        bf16x8 wf[4], nf[2];
        #pragma unroll
        for (int nt = 0; nt < 4; ++nt)
            wf[nt] = *(const bf16x8*)&w1t[(size_t)(jb + nt * 16 + r16) * K1
                                          + koff + ks * 32 + quad * 8];
        #pragma unroll
        for (int mt = 0; mt < 2; ++mt)
            nf[mt] = *(const bf16x8*)&g_nodef_bf[(size_t)(n0 + mt * 16 + r16) * ND
                                                 + ks * 32 + quad * 8];
        #pragma unroll
        for (int mt = 0; mt < 2; ++mt)
            #pragma unroll
            for (int nt = 0; nt < 4; ++nt)
                acc[mt][nt] = __builtin_amdgcn_mfma_f32_16x16x32_bf16(
                    wf[nt], nf[mt], acc[mt][nt], 0, 0, 0);
    }

    #pragma unroll
    for (int nt = 0; nt < 4; ++nt) {
        int j0 = cb + jb + nt * 16 + quad * 4;
        #pragma unroll
        for (int mt = 0; mt < 2; ++mt) {
            int m = n0 + mt * 16 + r16;
            ushort4 o;
            o.x = f2bf(acc[mt][nt][0]); o.y = f2bf(acc[mt][nt][1]);
            o.z = f2bf(acc[mt][nt][2]); o.w = f2bf(acc[mt][nt][3]);
            *(ushort4*)&g_Pb[(size_t)m * 512 + j0] = o;
        }
    }
}

// ---------- edge MLP: sE aliased under sH (sE dead after GEMM1) -> 33.8 KB, 4 blocks/CU ----------
#define EK_SMEM (TME * LDH * 2)   // 33,792; sE aliases the first 8,192 B

__global__ __launch_bounds__(512, 8) void edge_mlp_mfma(
    const int*            __restrict__ eidx,
    const float*          __restrict__ edgef,
    const int*            __restrict__ perm,
    const unsigned short* __restrict__ w1t,       // [256][320] bf16 n-major
    const float*          __restrict__ b1m,
    float* __restrict__ agg)                      // aggH: [BN][256] fp32
{
    __shared__ __align__(16) char smem[EK_SMEM];
    unsigned short* sE = (unsigned short*)smem;   // [0, 8192)  — dead after GEMM1
    unsigned short* sH = (unsigned short*)smem;   // [0, 33792) — written after barrier
    __shared__ int s_src[TME];
    __shared__ int s_dst[TME];
    __shared__ int s_eid[TME];

    const int tid  = threadIdx.x;
    const int wave = tid >> 6;
    const int lane = tid & 63;
    const int quad = lane >> 4;
    const int r16  = lane & 15;
    const int be0  = blockIdx.x * TME;

    if (tid < TME) {
        int eid = perm[be0 + tid];
        int b   = eid / E_EDGES;
        int2 se = ((const int2*)eidx)[eid];
        s_eid[tid] = eid;
        s_src[tid] = b * N_NODES + se.x;
        s_dst[tid] = b * N_NODES + se.y;
    }

    // GEMM1 weight A-frags (k-rows 256..319 of W1m) + biases: issue early.
    const unsigned short* wB1 = w1t + (size_t)(wave * 32) * K1 + 256;
    bf16x8 wf00 = *(const bf16x8*)&wB1[(size_t)r16        * K1 + quad * 8];
    bf16x8 wf01 = *(const bf16x8*)&wB1[(size_t)r16        * K1 + 32 + quad * 8];
    bf16x8 wf10 = *(const bf16x8*)&wB1[(size_t)(16 + r16) * K1 + quad * 8];
    bf16x8 wf11 = *(const bf16x8*)&wB1[(size_t)(16 + r16) * K1 + 32 + quad * 8];
    float4 bb0 = *(const float4*)&b1m[wave * 32 + quad * 4];
    float4 bb1 = *(const float4*)&b1m[wave * 32 + 16 + quad * 4];

    __syncthreads();   // s_src/s_dst/s_eid visible

    // stage edge features fp32 -> bf16 panels: 2 x [64 rows x 32 k]
    {
        int row = tid >> 3;
        int c0  = (tid & 7) * 8;        // 0..56
        const float* fp = edgef + (size_t)s_eid[row] * ED + c0;
        float4 v0 = *(const float4*)fp;
        float4 v1 = *(const float4*)(fp + 4);
        ushort4 o0, o1;
        o0.x = f2bf(v0.x); o0.y = f2bf(v0.y); o0.z = f2bf(v0.z); o0.w = f2bf(v0.w);
        o1.x = f2bf(v1.x); o1.y = f2bf(v1.y); o1.z = f2bf(v1.z); o1.w = f2bf(v1.w);
        int p2 = c0 >> 5, kk = c0 & 31;
        *(ushort4*)&sE[p2 * 2048 + row * 32 + kk]     = o0;
        *(ushort4*)&sE[p2 * 2048 + row * 32 + kk + 4] = o1;
    }
    __syncthreads();   // sE ready

    f32x4 acc[4][2];
    #pragma unroll
    for (int mt = 0; mt < 4; ++mt)
        #pragma unroll
        for (int nt = 0; nt < 2; ++nt)
            acc[mt][nt] = (f32x4){0.f, 0.f, 0.f, 0.f};

    // ---- GEMM1: K=64 on edge features (A=weights, B=edge rows) ----
    #pragma unroll
    for (int mt = 0; mt < 4; ++mt) {
        bf16x8 e0 = *(const bf16x8*)&sE[(mt * 16 + r16) * 32 + quad * 8];
        bf16x8 e1 = *(const bf16x8*)&sE[2048 + (mt * 16 + r16) * 32 + quad * 8];
        acc[mt][0] = __builtin_amdgcn_mfma_f32_16x16x32_bf16(wf00, e0, acc[mt][0], 0, 0, 0);
        acc[mt][1] = __builtin_amdgcn_mfma_f32_16x16x32_bf16(wf10, e0, acc[mt][1], 0, 0, 0);
        acc[mt][0] = __builtin_amdgcn_mfma_f32_16x16x32_bf16(wf01, e1, acc[mt][0], 0, 0, 0);
        acc[mt][1] = __builtin_amdgcn_mfma_f32_16x16x32_bf16(wf11, e1, acc[mt][1], 0, 0, 0);
    }
    __syncthreads();   // all waves done reading sE (sH overwrites it)

    // ---- gather-add epilogue: + P[src] + P[dst] + b1, gelu -> sH (bf16 P, ushort4) ----
    #pragma unroll
    for (int mt = 0; mt < 4; ++mt) {
        int m = mt * 16 + r16;
        const unsigned short* pS = &g_Pb[(size_t)s_src[m] * 512];
        const unsigned short* pD = &g_Pb[(size_t)s_dst[m] * 512 + 256];
        #pragma unroll
        for (int nt = 0; nt < 2; ++nt) {
            int n0 = wave * 32 + nt * 16 + quad * 4;
            float4 bb = nt ? bb1 : bb0;
            ushort4 us = *(const ushort4*)(pS + n0);
            ushort4 ud = *(const ushort4*)(pD + n0);
            ushort4 o;
            o.x = f2bf(gelu_tanh(acc[mt][nt][0] + bf2f(us.x) + bf2f(ud.x) + bb.x));
            o.y = f2bf(gelu_tanh(acc[mt][nt][1] + bf2f(us.y) + bf2f(ud.y) + bb.y));
            o.z = f2bf(gelu_tanh(acc[mt][nt][2] + bf2f(us.z) + bf2f(ud.z) + bb.z));
            o.w = f2bf(gelu_tanh(acc[mt][nt][3] + bf2f(us.w) + bf2f(ud.w) + bb.w));
            *(ushort4*)&sH[m * LDH + n0] = o;
        }
    }
    __syncthreads();   // sH visible to all waves

    // ---- run-reduce h into agg (sorted dst -> compacted atomics) ----
    {
        const int cc = tid & 255;          // column
        const int r0 = (tid >> 8) * 32;    // row-half base
        int   cur  = s_dst[r0];
        float racc = 0.f;
        for (int mb = 0; mb < 32; mb += 8) {
            float v[8];
            #pragma unroll
            for (int j = 0; j < 8; ++j)
                v[j] = bf2f(sH[(r0 + mb + j) * LDH + cc]);
            #pragma unroll
            for (int j = 0; j < 8; ++j) {
                int d = s_dst[r0 + mb + j];
                if (d != cur) {
                    atomicAdd(&agg[(size_t)cur * HID + cc], racc);
                    cur = d; racc = v[j];
                } else {
                    racc += v[j];
                }
            }
        }
        atomicAdd(&agg[(size_t)cur * HID + cc], racc);
    }
}

// ---------- node MLP: 256 thr / 4 waves, TM=32 -> 625 blocks exactly ----------
// u_pre = nodef@W1u_a + aggH@Wc + hist*bc + b1u; out = gelu(u_pre)@W2u + b2u
// hist[row] recovered from post-scatter g_offs (inclusive prefix diff).
__global__ __launch_bounds__(256, 4) void node_mlp_mfma(
    const float* __restrict__ agg,
    const float* __restrict__ b1u,
    const float* __restrict__ b2u,
    float* __restrict__ out)
{
    __shared__ __align__(16) unsigned short sH[TMN * LDH];   // 16,896 B

    const int tid  = threadIdx.x;
    const int wave = tid >> 6;     // 0..3: owns 64 L1-cols / 32 L2-cols
    const int lane = tid & 63;
    const int quad = lane >> 4;
    const int r16  = lane & 15;
    const int n0   = blockIdx.x * TMN;

    f32x4 acc[2][4];
    #pragma unroll
    for (int mt = 0; mt < 2; ++mt)
        #pragma unroll
        for (int nt = 0; nt < 4; ++nt)
            acc[mt][nt] = (f32x4){0.f, 0.f, 0.f, 0.f};

    // ---- L1 part A: k in [0,128) from g_nodef_bf ----
    for (int ks = 0; ks < 4; ++ks) {
        bf16x8 wf[4], nf[2];
        #pragma unroll
        for (int nt = 0; nt < 4; ++nt)
            wf[nt] = *(const bf16x8*)&g_w1c[(size_t)(wave * 64 + nt * 16 + r16) * K1U
                                            + ks * 32 + quad * 8];
        #pragma unroll
        for (int mt = 0; mt < 2; ++mt)
            nf[mt] = *(const bf16x8*)&g_nodef_bf[(size_t)(n0 + mt * 16 + r16) * ND
                                                 + ks * 32 + quad * 8];
        #pragma unroll
        for (int mt = 0; mt < 2; ++mt)
            #pragma unroll
            for (int nt = 0; nt < 4; ++nt)
                acc[mt][nt] = __builtin_amdgcn_mfma_f32_16x16x32_bf16(
                    wf[nt], nf[mt], acc[mt][nt], 0, 0, 0);
    }
    // ---- L1 part B: k in [128,384) = aggH @ Wc (fp32 -> bf16 in regs) ----
    for (int ks = 0; ks < 8; ++ks) {
        bf16x8 wf[4], nf[2];
        #pragma unroll
        for (int nt = 0; nt < 4; ++nt)
            wf[nt] = *(const bf16x8*)&g_w1c[(size_t)(wave * 64 + nt * 16 + r16) * K1U
                                            + (4 + ks) * 32 + quad * 8];
        #pragma unroll
        for (int mt = 0; mt < 2; ++mt) {
            const float* fp = &agg[(size_t)(n0 + mt * 16 + r16) * HID + ks * 32 + quad * 8];
            float4 v0 = *(const float4*)fp;
            float4 v1 = *(const float4*)(fp + 4);
            union { bf16x8 v; ushort4 u[2]; } cv;
            cv.u[0] = (ushort4){f2bf(v0.x), f2bf(v0.y), f2bf(v0.z), f2bf(v0.w)};
            cv.u[1] = (ushort4){f2bf(v1.x), f2bf(v1.y), f2bf(v1.z), f2bf(v1.w)};
            nf[mt] = cv.v;
        }
        #pragma unroll
        for (int mt = 0; mt < 2; ++mt)
            #pragma unroll
            for (int nt = 0; nt < 4; ++nt)
                acc[mt][nt] = __builtin_amdgcn_mfma_f32_16x16x32_bf16(
                    wf[nt], nf[mt], acc[mt][nt], 0, 0, 0);
    }

    // ---- L1 epilogue -> sH (ushort4 stores), bias = b1u + hist*bc ----
    #pragma unroll
    for (int nt = 0; nt < 4; ++nt) {
        int nn0 = wave * 64 + nt * 16 + quad * 4;
        float4 bb = *(const float4*)&b1u[nn0];
        float4 bc = *(const float4*)&g_bc[nn0];
        #pragma unroll
        for (int mt = 0; mt < 2; ++mt) {
            int row  = n0 + mt * 16 + r16;
            int incl = g_offs[row];
            int prev = (row > 0) ? g_offs[row - 1] : 0;
            float hv = (float)(incl - prev);
            int m = mt * 16 + r16;
            ushort4 o;
            o.x = f2bf(gelu_tanh(acc[mt][nt][0] + bb.x + hv * bc.x));
            o.y = f2bf(gelu_tanh(acc[mt][nt][1] + bb.y + hv * bc.y));
            o.z = f2bf(gelu_tanh(acc[mt][nt][2] + bb.z + hv * bc.z));
            o.w = f2bf(gelu_tanh(acc[mt][nt][3] + bb.w + hv * bc.w));
            *(ushort4*)&sH[m * LDH + nn0] = o;
        }
    }
    __syncthreads();

    f32x4 acc2[2][2];
    #pragma unroll
    for (int mt = 0; mt < 2; ++mt)
        #pragma unroll
        for (int nt = 0; nt < 2; ++nt)
            acc2[mt][nt] = (f32x4){0.f, 0.f, 0.f, 0.f};

    for (int ks = 0; ks < K2 / 32; ++ks) {
        bf16x8 wf2[2], hf[2];
        #pragma unroll
        for (int nt = 0; nt < 2; ++nt)
            wf2[nt] = *(const bf16x8*)&g_w2ut[(size_t)(wave * 32 + nt * 16 + r16) * K2
                                              + ks * 32 + quad * 8];
        #pragma unroll
        for (int mt = 0; mt < 2; ++mt)
            hf[mt] = *(const bf16x8*)&sH[(mt * 16 + r16) * LDH + ks * 32 + quad * 8];
        #pragma unroll
        for (int mt = 0; mt < 2; ++mt)
            #pragma unroll
            for (int nt = 0; nt < 2; ++nt)
                acc2[mt][nt] = __builtin_amdgcn_mfma_f32_16x16x32_bf16(
                    wf2[nt], hf[mt], acc2[mt][nt], 0, 0, 0);
    }

    // ---- L2 epilogue -> out (float4 stores) ----
    #pragma unroll
    for (int nt = 0; nt < 2; ++nt) {
        int j0 = wave * 32 + nt * 16 + quad * 4;
        float4 bb = *(const float4*)&b2u[j0];
        #pragma unroll
        for (int mt = 0; mt < 2; ++mt) {
            int row = n0 + mt * 16 + r16;
            float4 v = {acc2[mt][nt][0] + bb.x, acc2[mt][nt][1] + bb.y,
                        acc2[mt][nt][2] + bb.z, acc2[mt][nt][3] + bb.w};
            *(float4*)&out[(size_t)row * NOUT + j0] = v;
        }
    }
}

// ---------- launch ----------
// ws: aggH [0 .. 20,480,000). d_out stash (read only before node_mlp_mfma runs):
//   w1t  [5,120,000 .. 5,283,840)
//   perm [5,574,912 .. 6,854,912)
// statics: g_Pb, g_nodef_bf, g_w1c, g_w2ut, g_bc, g_hist, g_offs.
// 5 launches: prep_hist | scan20k | pgemm_scatter | edge | node

extern "C" void kernel_launch(void* const* d_in, const int* in_sizes, int n_in,
                              void* d_out, int out_size, void* d_ws, size_t ws_size,
                              hipStream_t stream) {
    const float* nodef = (const float*)d_in[0];
    const int*   eidx  = (const int*)  d_in[1];
    const float* edgef = (const float*)d_in[2];
    const float* W1m   = (const float*)d_in[3];
    const float* b1m   = (const float*)d_in[4];
    const float* W2m   = (const float*)d_in[5];
    const float* b2m   = (const float*)d_in[6];
    const float* W1u   = (const float*)d_in[7];
    const float* b1u   = (const float*)d_in[8];
    const float* W2u   = (const float*)d_in[9];
    const float* b2u   = (const float*)d_in[10];
    float* out = (float*)d_out;

    char* wsb = (char*)d_ws;
    float* agg = (float*)wsb;

    char* ob = (char*)d_out;
    unsigned short* w1t  = (unsigned short*)(ob + 5120000);
    int* perm            = (int*)(ob + 5574912);

    prep_hist<<<BN * ND / 4 / 256, 256, 0, stream>>>(
        nodef, eidx, agg, W1m, w1t, W1u, W2u, W2m, b2m);

    scan20k<<<1, 1024, 0, stream>>>();

    pgemm_scatter<<<BN / TMN, 512, 0, stream>>>(w1t, eidx, perm);

    edge_mlp_mfma<<<BE / TME, 512, 0, stream>>>(
        eidx, edgef, perm, w1t, b1m, agg);

    node_mlp_mfma<<<BN / TMN, 256, 0, stream>>>(agg, b1u, b2u, out);
}